// Round 1
// baseline (13395.871 us; speedup 1.0000x reference)
//
#include <hip/hip_runtime.h>
#include <cstdint>
#include <cmath>

constexpr int BATCH = 64;
constexpr int T     = 512;
constexpr int N     = 1024;

// ---------------------------------------------------------------------------
// W_self = 0.5*(W + W^T)
// ---------------------------------------------------------------------------
__global__ __launch_bounds__(256) void symm_k(const float* __restrict__ W,
                                              float* __restrict__ Ws) {
  int j = blockIdx.x * 16 + (threadIdx.x & 15);
  int i = blockIdx.y * 16 + (threadIdx.x >> 4);
  Ws[(size_t)i * N + j] = 0.5f * (W[(size_t)i * N + j] + W[(size_t)j * N + i]);
}

// ---------------------------------------------------------------------------
// x_proj = A (M x K) . B^T where B = W_input (N x K) row-major.
// C[m][n] = dot(A_row_m, B_row_n).  Classic 128x128 tile, BK=16, 8x8 micro.
// ---------------------------------------------------------------------------
__global__ __launch_bounds__(256) void xproj_gemm(const float* __restrict__ A,
                                                  const float* __restrict__ B,
                                                  float* __restrict__ C,
                                                  int M) {
  constexpr int BM = 128, BN = 128, BK = 16;
  __shared__ float As[BK][BM + 4];
  __shared__ float Bs[BK][BN + 4];

  const int tid = threadIdx.x;
  const int bm = blockIdx.y, bn = blockIdx.x;
  const int tx = tid & 15, ty = tid >> 4;
  const int K = N;

  float acc[8][8];
#pragma unroll
  for (int i = 0; i < 8; ++i)
#pragma unroll
    for (int j = 0; j < 8; ++j) acc[i][j] = 0.f;

  for (int kt = 0; kt < K; kt += BK) {
#pragma unroll
    for (int s = 0; s < 2; ++s) {
      int f = tid + s * 256;          // 0..511
      int row = f >> 2, kq = f & 3;   // row 0..127, kq 0..3 (float4 along k)
      float4 a = *reinterpret_cast<const float4*>(
          &A[(size_t)(bm * BM + row) * K + kt + kq * 4]);
      As[kq * 4 + 0][row] = a.x;
      As[kq * 4 + 1][row] = a.y;
      As[kq * 4 + 2][row] = a.z;
      As[kq * 4 + 3][row] = a.w;
      float4 b = *reinterpret_cast<const float4*>(
          &B[(size_t)(bn * BN + row) * K + kt + kq * 4]);
      Bs[kq * 4 + 0][row] = b.x;
      Bs[kq * 4 + 1][row] = b.y;
      Bs[kq * 4 + 2][row] = b.z;
      Bs[kq * 4 + 3][row] = b.w;
    }
    __syncthreads();

#pragma unroll
    for (int k = 0; k < BK; ++k) {
      float a[8], b[8];
      *reinterpret_cast<float4*>(&a[0]) =
          *reinterpret_cast<const float4*>(&As[k][ty * 8]);
      *reinterpret_cast<float4*>(&a[4]) =
          *reinterpret_cast<const float4*>(&As[k][ty * 8 + 4]);
      *reinterpret_cast<float4*>(&b[0]) =
          *reinterpret_cast<const float4*>(&Bs[k][tx * 8]);
      *reinterpret_cast<float4*>(&b[4]) =
          *reinterpret_cast<const float4*>(&Bs[k][tx * 8 + 4]);
#pragma unroll
      for (int i = 0; i < 8; ++i)
#pragma unroll
        for (int j = 0; j < 8; ++j) acc[i][j] = fmaf(a[i], b[j], acc[i][j]);
    }
    __syncthreads();
  }

#pragma unroll
  for (int i = 0; i < 8; ++i) {
    size_t row = (size_t)bm * BM + ty * 8 + i;
#pragma unroll
    for (int j = 0; j < 8; j += 4) {
      *reinterpret_cast<float4*>(&C[row * N + bn * BN + tx * 8 + j]) =
          *reinterpret_cast<const float4*>(&acc[i][j]);
    }
  }
}

// ---------------------------------------------------------------------------
// One recurrence step.  out[:, t, :] currently holds x_proj; out[:, t-1, :]
// holds h_{t-1}.  Computes h_t = tanh(W_self . h_{t-1} + x_proj_t) in place.
// Grid: 256 WGs; WG g owns output columns 4g..4g+3 for ALL 64 batches.
// Within WG: wave w (0..3) -> column 4g+w; lane -> batch.
// ---------------------------------------------------------------------------
__global__ __launch_bounds__(256) void rnn_step(float* __restrict__ out,
                                                const float* __restrict__ Ws,
                                                int t) {
  const int g = blockIdx.x;
  const int tid = threadIdx.x;
  const int lane = tid & 63;   // batch (compute phase)
  const int w = tid >> 6;      // column within group
  const int m0 = g * 4;
  const size_t TN = (size_t)T * N;

  __shared__ float Wl[4 * N];      // 16 KiB: 4 W rows, flat
  __shared__ float hl[64][65];     // h chunk, k-major, +1 pad
  __shared__ float xl[64][5];      // xp in / h_new out staging

  // stage W rows (coalesced, flat)
  if (t > 0) {
    const float4* src = reinterpret_cast<const float4*>(Ws + (size_t)m0 * N);
    float4* dst = reinterpret_cast<float4*>(Wl);
#pragma unroll
    for (int s = 0; s < 4; ++s) dst[tid + 256 * s] = src[tid + 256 * s];
  }
  // stage xp (coalesced-ish 16B segments)
  {
    int b = tid >> 2, c = tid & 3;
    xl[b][c] = out[(size_t)b * TN + (size_t)t * N + m0 + c];
  }
  __syncthreads();

  float acc0 = 0.f, acc1 = 0.f, acc2 = 0.f, acc3 = 0.f;
  if (t > 0) {
    const float* hprev = out + (size_t)(t - 1) * N;
    for (int kc = 0; kc < N; kc += 64) {
      // stage h chunk [64 k][64 b] transposed
      int b = tid >> 2, kq = tid & 3;
      const float* src = hprev + (size_t)b * TN + kc + kq * 16;
#pragma unroll
      for (int j = 0; j < 4; ++j) {
        float4 v = *reinterpret_cast<const float4*>(src + 4 * j);
        int k_ = kq * 16 + 4 * j;
        hl[k_ + 0][b] = v.x;
        hl[k_ + 1][b] = v.y;
        hl[k_ + 2][b] = v.z;
        hl[k_ + 3][b] = v.w;
      }
      __syncthreads();
      const float* wrow = Wl + w * N + kc;
#pragma unroll
      for (int k_ = 0; k_ < 64; k_ += 4) {
        acc0 = fmaf(wrow[k_ + 0], hl[k_ + 0][lane], acc0);
        acc1 = fmaf(wrow[k_ + 1], hl[k_ + 1][lane], acc1);
        acc2 = fmaf(wrow[k_ + 2], hl[k_ + 2][lane], acc2);
        acc3 = fmaf(wrow[k_ + 3], hl[k_ + 3][lane], acc3);
      }
      __syncthreads();
    }
  }

  float preact = (acc0 + acc1) + (acc2 + acc3) + xl[lane][w];
  float hv = tanhf(preact);
  __syncthreads();
  xl[lane][w] = hv;
  __syncthreads();
  {
    int b = tid >> 2, c = tid & 3;
    out[(size_t)b * TN + (size_t)t * N + m0 + c] = xl[b][c];
  }
}

// ---------------------------------------------------------------------------
extern "C" void kernel_launch(void* const* d_in, const int* in_sizes, int n_in,
                              void* d_out, int out_size, void* d_ws,
                              size_t ws_size, hipStream_t stream) {
  const float* in_seq  = (const float*)d_in[0];  // (64,512,1024)
  const float* W_lower = (const float*)d_in[1];  // (1024,1024)
  const float* W_input = (const float*)d_in[2];  // (1024,1024)
  float* out = (float*)d_out;                    // (64,512,1024)
  float* Ws  = (float*)d_ws;                     // 4 MiB scratch

  symm_k<<<dim3(N / 16, N / 16), 256, 0, stream>>>(W_lower, Ws);
  xproj_gemm<<<dim3(N / 128, (BATCH * T) / 128), 256, 0, stream>>>(
      in_seq, W_input, out, BATCH * T);
  for (int t = 0; t < T; ++t)
    rnn_step<<<256, 256, 0, stream>>>(out, Ws, t);
}

// Round 2
// 9712.720 us; speedup vs baseline: 1.3792x; 1.3792x over previous
//
#include <hip/hip_runtime.h>
#include <cstdint>
#include <cmath>

constexpr int BATCH = 64;
constexpr int T     = 512;
constexpr int N     = 1024;
constexpr int NWG   = 256;   // persistent workgroups (== CU count)
constexpr int MB    = 16;    // batches per WG
constexpr int MM    = 16;    // output columns per WG

__device__ int g_cnt;        // grid barrier counter (re-zeroed every launch)

// ---------------------------------------------------------------------------
// W_self = 0.5*(W + W^T); also re-initializes the grid-barrier counter.
// ---------------------------------------------------------------------------
__global__ __launch_bounds__(256) void symm_k(const float* __restrict__ W,
                                              float* __restrict__ Ws) {
  if (blockIdx.x == 0 && blockIdx.y == 0 && threadIdx.x == 0)
    __hip_atomic_store(&g_cnt, 0, __ATOMIC_RELAXED, __HIP_MEMORY_SCOPE_AGENT);
  int j = blockIdx.x * 16 + (threadIdx.x & 15);
  int i = blockIdx.y * 16 + (threadIdx.x >> 4);
  Ws[(size_t)i * N + j] = 0.5f * (W[(size_t)i * N + j] + W[(size_t)j * N + i]);
}

// ---------------------------------------------------------------------------
// x_proj = A (M x K) . B^T, B = W_input (N x K) row-major. 128x128 tile.
// ---------------------------------------------------------------------------
__global__ __launch_bounds__(256) void xproj_gemm(const float* __restrict__ A,
                                                  const float* __restrict__ B,
                                                  float* __restrict__ C,
                                                  int M) {
  constexpr int BM = 128, BN = 128, BK = 16;
  __shared__ float As[BK][BM + 4];
  __shared__ float Bs[BK][BN + 4];

  const int tid = threadIdx.x;
  const int bm = blockIdx.y, bn = blockIdx.x;
  const int tx = tid & 15, ty = tid >> 4;
  const int K = N;

  float acc[8][8];
#pragma unroll
  for (int i = 0; i < 8; ++i)
#pragma unroll
    for (int j = 0; j < 8; ++j) acc[i][j] = 0.f;

  for (int kt = 0; kt < K; kt += BK) {
#pragma unroll
    for (int s = 0; s < 2; ++s) {
      int f = tid + s * 256;
      int row = f >> 2, kq = f & 3;
      float4 a = *reinterpret_cast<const float4*>(
          &A[(size_t)(bm * BM + row) * K + kt + kq * 4]);
      As[kq * 4 + 0][row] = a.x;
      As[kq * 4 + 1][row] = a.y;
      As[kq * 4 + 2][row] = a.z;
      As[kq * 4 + 3][row] = a.w;
      float4 b = *reinterpret_cast<const float4*>(
          &B[(size_t)(bn * BN + row) * K + kt + kq * 4]);
      Bs[kq * 4 + 0][row] = b.x;
      Bs[kq * 4 + 1][row] = b.y;
      Bs[kq * 4 + 2][row] = b.z;
      Bs[kq * 4 + 3][row] = b.w;
    }
    __syncthreads();

#pragma unroll
    for (int k = 0; k < BK; ++k) {
      float a[8], b[8];
      *reinterpret_cast<float4*>(&a[0]) =
          *reinterpret_cast<const float4*>(&As[k][ty * 8]);
      *reinterpret_cast<float4*>(&a[4]) =
          *reinterpret_cast<const float4*>(&As[k][ty * 8 + 4]);
      *reinterpret_cast<float4*>(&b[0]) =
          *reinterpret_cast<const float4*>(&Bs[k][tx * 8]);
      *reinterpret_cast<float4*>(&b[4]) =
          *reinterpret_cast<const float4*>(&Bs[k][tx * 8 + 4]);
#pragma unroll
      for (int i = 0; i < 8; ++i)
#pragma unroll
        for (int j = 0; j < 8; ++j) acc[i][j] = fmaf(a[i], b[j], acc[i][j]);
    }
    __syncthreads();
  }

#pragma unroll
  for (int i = 0; i < 8; ++i) {
    size_t row = (size_t)bm * BM + ty * 8 + i;
#pragma unroll
    for (int j = 0; j < 8; j += 4) {
      *reinterpret_cast<float4*>(&C[row * N + bn * BN + tx * 8 + j]) =
          *reinterpret_cast<const float4*>(&acc[i][j]);
    }
  }
}

// ---------------------------------------------------------------------------
// Persistent recurrence kernel.  Grid = 256 WGs x 256 threads, 1 WG/CU.
// WG (bg,mg): batches b0..b0+15, output cols m0..m0+15.
// W slice (16 rows x 1024) stays in LDS for all 512 steps.
// Per step: stage h[16][1024] slice + xp tile; 4x4 register micro-tile,
// k-split 16 across lanes, shuffle-reduce; device-wide barrier between steps.
// ---------------------------------------------------------------------------
__global__ __launch_bounds__(256) void rnn_persist(float* __restrict__ out,
                                                   const float* __restrict__ Ws) {
  const int tid = threadIdx.x;
  const int wg  = blockIdx.x;
  const int mg  = wg >> 2;          // 64 column groups
  const int bg  = wg & 3;           // 4 batch groups
  const int m0  = mg * MM;
  const int b0  = bg * MB;
  const size_t TN = (size_t)T * N;

  __shared__ float Wl[MM][N];       // 64 KiB, persistent
  __shared__ float hl[MB][N];       // 64 KiB, per-step h slice
  __shared__ float xl[MB][MM + 1];  // xp tile
  __shared__ float pre[MB][MM + 1]; // reduced preactivation

  // ---- load W slice once (coalesced, 64 KiB) ----
  {
    const float4* src = reinterpret_cast<const float4*>(Ws + (size_t)m0 * N);
    float4* dst = reinterpret_cast<float4*>(&Wl[0][0]);
#pragma unroll
    for (int s = 0; s < 16; ++s) dst[tid + 256 * s] = src[tid + 256 * s];
  }

  const int l  = tid & 63;          // lane
  const int w  = tid >> 6;          // wave -> batch quad
  const int tw = l & 3;             // m quad
  const int kp = l >> 2;            // k partition (16-way)
  const int rs = tid >> 4;          // staging row (batch-local)
  const int cs = tid & 15;          // staging col

  for (int t = 0; t < T; ++t) {
    // stage xp tile (out[:,t,:] still holds x_proj for our tile)
    xl[rs][cs] = out[(size_t)(b0 + rs) * TN + (size_t)t * N + m0 + cs];
    if (t > 0) {
      const float4* hsrc = reinterpret_cast<const float4*>(
          out + (size_t)(b0 + rs) * TN + (size_t)(t - 1) * N);
      float4* hdst = reinterpret_cast<float4*>(&hl[rs][0]);
#pragma unroll
      for (int jj = 0; jj < 16; ++jj) hdst[cs + 16 * jj] = hsrc[cs + 16 * jj];
    }
    __syncthreads();

    float pv;
    if (t > 0) {
      float acc[16];
#pragma unroll
      for (int i = 0; i < 16; ++i) acc[i] = 0.f;
#pragma unroll 2
      for (int j = 0; j < 16; ++j) {
        const int kb = j * 64 + kp * 4;
        float4 hv[4], wv[4];
#pragma unroll
        for (int i = 0; i < 4; ++i)
          hv[i] = *reinterpret_cast<const float4*>(&hl[w * 4 + i][kb]);
#pragma unroll
        for (int i = 0; i < 4; ++i)
          wv[i] = *reinterpret_cast<const float4*>(&Wl[tw * 4 + i][kb]);
#pragma unroll
        for (int bi = 0; bi < 4; ++bi)
#pragma unroll
          for (int mi = 0; mi < 4; ++mi) {
            float a = acc[bi * 4 + mi];
            a = fmaf(hv[bi].x, wv[mi].x, a);
            a = fmaf(hv[bi].y, wv[mi].y, a);
            a = fmaf(hv[bi].z, wv[mi].z, a);
            a = fmaf(hv[bi].w, wv[mi].w, a);
            acc[bi * 4 + mi] = a;
          }
      }
      // reduce over the 16 k-partitions (lanes differing in bits 2..5)
#pragma unroll
      for (int o = 4; o < 64; o <<= 1)
#pragma unroll
        for (int i = 0; i < 16; ++i) acc[i] += __shfl_xor(acc[i], o, 64);
      if (kp == 0) {
#pragma unroll
        for (int bi = 0; bi < 4; ++bi)
#pragma unroll
          for (int mi = 0; mi < 4; ++mi)
            pre[w * 4 + bi][tw * 4 + mi] = acc[bi * 4 + mi];
      }
      __syncthreads();
      pv = pre[rs][cs] + xl[rs][cs];
    } else {
      pv = xl[rs][cs];
    }

    out[(size_t)(b0 + rs) * TN + (size_t)t * N + m0 + cs] = tanhf(pv);

    if (t < T - 1) {
      __syncthreads();  // all stores of h_t issued; LDS free for restage
      if (tid == 0) {
        __hip_atomic_fetch_add(&g_cnt, 1, __ATOMIC_RELEASE,
                               __HIP_MEMORY_SCOPE_AGENT);
        const int target = (t + 1) * NWG;
        while (__hip_atomic_load(&g_cnt, __ATOMIC_RELAXED,
                                 __HIP_MEMORY_SCOPE_AGENT) < target)
          __builtin_amdgcn_s_sleep(2);
        __builtin_amdgcn_fence(__ATOMIC_ACQUIRE, "agent");
      }
      __syncthreads();
    }
  }
}

// ---------------------------------------------------------------------------
extern "C" void kernel_launch(void* const* d_in, const int* in_sizes, int n_in,
                              void* d_out, int out_size, void* d_ws,
                              size_t ws_size, hipStream_t stream) {
  const float* in_seq  = (const float*)d_in[0];  // (64,512,1024)
  const float* W_lower = (const float*)d_in[1];  // (1024,1024)
  const float* W_input = (const float*)d_in[2];  // (1024,1024)
  float* out = (float*)d_out;                    // (64,512,1024)
  float* Ws  = (float*)d_ws;                     // 4 MiB scratch

  symm_k<<<dim3(N / 16, N / 16), 256, 0, stream>>>(W_lower, Ws);
  xproj_gemm<<<dim3(N / 128, (BATCH * T) / 128), 256, 0, stream>>>(
      in_seq, W_input, out, BATCH * T);
  rnn_persist<<<NWG, 256, 0, stream>>>(out, Ws);
}

// Round 4
// 8343.560 us; speedup vs baseline: 1.6055x; 1.1641x over previous
//
#include <hip/hip_runtime.h>
#include <cstdint>
#include <cmath>

constexpr int BATCH = 64;
constexpr int T     = 512;
constexpr int N     = 1024;
constexpr int NWG   = 256;   // persistent workgroups (== CU count)
constexpr int MB    = 16;    // batches per WG
constexpr int MM    = 16;    // output columns per WG
constexpr int NP    = N + 4; // padded LDS row (breaks 32-bank stride)

typedef float f4 __attribute__((ext_vector_type(4)));  // native vec for nt ld/st

struct alignas(128) PadInt { int v; int pad[31]; };
__device__ PadInt g_cnt[4];   // per-batch-group arrival counters
__device__ PadInt g_flag[4];  // per-batch-group release epochs

// ---------------------------------------------------------------------------
// W_self = 0.5*(W + W^T); also re-initializes the barrier state.
// ---------------------------------------------------------------------------
__global__ __launch_bounds__(256) void symm_k(const float* __restrict__ W,
                                              float* __restrict__ Ws) {
  if (blockIdx.x == 0 && blockIdx.y == 0 && threadIdx.x < 4) {
    __hip_atomic_store(&g_cnt[threadIdx.x].v, 0, __ATOMIC_RELAXED,
                       __HIP_MEMORY_SCOPE_AGENT);
    __hip_atomic_store(&g_flag[threadIdx.x].v, 0, __ATOMIC_RELAXED,
                       __HIP_MEMORY_SCOPE_AGENT);
  }
  int j = blockIdx.x * 16 + (threadIdx.x & 15);
  int i = blockIdx.y * 16 + (threadIdx.x >> 4);
  Ws[(size_t)i * N + j] = 0.5f * (W[(size_t)i * N + j] + W[(size_t)j * N + i]);
}

// ---------------------------------------------------------------------------
// x_proj = A (M x K) . B^T, B = W_input (N x K) row-major. 128x128 tile.
// ---------------------------------------------------------------------------
__global__ __launch_bounds__(256) void xproj_gemm(const float* __restrict__ A,
                                                  const float* __restrict__ B,
                                                  float* __restrict__ C,
                                                  int M) {
  constexpr int BM = 128, BN = 128, BK = 16;
  __shared__ float As[BK][BM + 4];
  __shared__ float Bs[BK][BN + 4];

  const int tid = threadIdx.x;
  const int bm = blockIdx.y, bn = blockIdx.x;
  const int tx = tid & 15, ty = tid >> 4;
  const int K = N;

  float acc[8][8];
#pragma unroll
  for (int i = 0; i < 8; ++i)
#pragma unroll
    for (int j = 0; j < 8; ++j) acc[i][j] = 0.f;

  for (int kt = 0; kt < K; kt += BK) {
#pragma unroll
    for (int s = 0; s < 2; ++s) {
      int f = tid + s * 256;
      int row = f >> 2, kq = f & 3;
      float4 a = *reinterpret_cast<const float4*>(
          &A[(size_t)(bm * BM + row) * K + kt + kq * 4]);
      As[kq * 4 + 0][row] = a.x;
      As[kq * 4 + 1][row] = a.y;
      As[kq * 4 + 2][row] = a.z;
      As[kq * 4 + 3][row] = a.w;
      float4 b = *reinterpret_cast<const float4*>(
          &B[(size_t)(bn * BN + row) * K + kt + kq * 4]);
      Bs[kq * 4 + 0][row] = b.x;
      Bs[kq * 4 + 1][row] = b.y;
      Bs[kq * 4 + 2][row] = b.z;
      Bs[kq * 4 + 3][row] = b.w;
    }
    __syncthreads();

#pragma unroll
    for (int k = 0; k < BK; ++k) {
      float a[8], b[8];
      *reinterpret_cast<float4*>(&a[0]) =
          *reinterpret_cast<const float4*>(&As[k][ty * 8]);
      *reinterpret_cast<float4*>(&a[4]) =
          *reinterpret_cast<const float4*>(&As[k][ty * 8 + 4]);
      *reinterpret_cast<float4*>(&b[0]) =
          *reinterpret_cast<const float4*>(&Bs[k][tx * 8]);
      *reinterpret_cast<float4*>(&b[4]) =
          *reinterpret_cast<const float4*>(&Bs[k][tx * 8 + 4]);
#pragma unroll
      for (int i = 0; i < 8; ++i)
#pragma unroll
        for (int j = 0; j < 8; ++j) acc[i][j] = fmaf(a[i], b[j], acc[i][j]);
    }
    __syncthreads();
  }

#pragma unroll
  for (int i = 0; i < 8; ++i) {
    size_t row = (size_t)bm * BM + ty * 8 + i;
#pragma unroll
    for (int j = 0; j < 8; j += 4) {
      *reinterpret_cast<float4*>(&C[row * N + bn * BN + tx * 8 + j]) =
          *reinterpret_cast<const float4*>(&acc[i][j]);
    }
  }
}

// ---------------------------------------------------------------------------
// Persistent recurrence.  Grid = 256 WGs x 256 threads, 1 WG/CU.
// WG (bg,mg): batches bg*16.., cols mg*16..; W slice resident in LDS.
// Batch groups are independent -> 4 independent 64-WG barriers.
// ---------------------------------------------------------------------------
__global__ __launch_bounds__(256) void rnn_persist(float* __restrict__ out,
                                                   const float* __restrict__ Ws) {
  const int tid = threadIdx.x;
  const int wg  = blockIdx.x;
  const int mg  = wg >> 2;          // 64 column groups
  const int bg  = wg & 3;           // 4 batch groups
  const int m0  = mg * MM;
  const int b0  = bg * MB;
  const size_t TN = (size_t)T * N;

  __shared__ float Wl[MM][NP];      // ~64 KiB, persistent, padded
  __shared__ float hl[MB][NP];      // ~64 KiB, per-step h slice, padded
  __shared__ float pre[MB][MM + 1]; // reduced preactivation

  // ---- load W slice once (row-wise, coalesced) ----
#pragma unroll
  for (int r = 0; r < MM; ++r) {
    const float4* src = reinterpret_cast<const float4*>(Ws + (size_t)(m0 + r) * N);
    reinterpret_cast<float4*>(&Wl[r][0])[tid] = src[tid];
  }

  const int l  = tid & 63;          // lane
  const int w  = tid >> 6;          // wave -> batch quad
  const int tw = l & 3;             // m quad
  const int kp = l >> 2;            // k partition (16-way)
  const int rs = tid >> 4;          // output row (batch-local)
  const int cs = tid & 15;          // output col

  float* myout = out + (size_t)(b0 + rs) * TN + m0 + cs;

  // prefetch xp for t=0 (read-only input; safe any time)
  float xpr = __builtin_nontemporal_load(myout);

  for (int t = 0; t < T; ++t) {
    if (t > 0) {
      const f4* hsrc = reinterpret_cast<const f4*>(
          out + (size_t)(b0 + rs) * TN + (size_t)(t - 1) * N);
      f4* hdst = reinterpret_cast<f4*>(&hl[rs][0]);
#pragma unroll
      for (int jj = 0; jj < 16; ++jj)
        hdst[cs + 16 * jj] = __builtin_nontemporal_load(hsrc + cs + 16 * jj);
      __syncthreads();

      float acc[16];
#pragma unroll
      for (int i = 0; i < 16; ++i) acc[i] = 0.f;
#pragma unroll 2
      for (int j = 0; j < 16; ++j) {
        const int kb = j * 64 + kp * 4;
        float4 hv[4], wv[4];
#pragma unroll
        for (int i = 0; i < 4; ++i)
          hv[i] = *reinterpret_cast<const float4*>(&hl[w * 4 + i][kb]);
#pragma unroll
        for (int i = 0; i < 4; ++i)
          wv[i] = *reinterpret_cast<const float4*>(&Wl[tw * 4 + i][kb]);
#pragma unroll
        for (int bi = 0; bi < 4; ++bi)
#pragma unroll
          for (int mi = 0; mi < 4; ++mi) {
            float a = acc[bi * 4 + mi];
            a = fmaf(hv[bi].x, wv[mi].x, a);
            a = fmaf(hv[bi].y, wv[mi].y, a);
            a = fmaf(hv[bi].z, wv[mi].z, a);
            a = fmaf(hv[bi].w, wv[mi].w, a);
            acc[bi * 4 + mi] = a;
          }
      }
      // reduce over the 16 k-partitions (lanes differing in bits 2..5)
#pragma unroll
      for (int o = 4; o < 64; o <<= 1)
#pragma unroll
        for (int i = 0; i < 16; ++i) acc[i] += __shfl_xor(acc[i], o, 64);
      if (kp == 0) {
#pragma unroll
        for (int bi = 0; bi < 4; ++bi)
#pragma unroll
          for (int mi = 0; mi < 4; ++mi)
            pre[w * 4 + bi][tw * 4 + mi] = acc[bi * 4 + mi];
      }
      __syncthreads();
    }

    float pv = (t > 0) ? (pre[rs][cs] + xpr) : xpr;
    __builtin_nontemporal_store(tanhf(pv), myout + (size_t)t * N);

    if (t < T - 1) {
      // prefetch next xp while stores drain (still x_proj until step t+1 ends)
      xpr = __builtin_nontemporal_load(myout + (size_t)(t + 1) * N);
      __syncthreads();  // all waves' h_t stores issued
      if (tid == 0) {
        int old = __hip_atomic_fetch_add(&g_cnt[bg].v, 1, __ATOMIC_RELEASE,
                                         __HIP_MEMORY_SCOPE_AGENT);
        if (old == (t + 1) * 64 - 1) {
          // last arriver in this batch group: publish epoch
          __hip_atomic_store(&g_flag[bg].v, t + 1, __ATOMIC_RELEASE,
                             __HIP_MEMORY_SCOPE_AGENT);
        } else {
          while (__hip_atomic_load(&g_flag[bg].v, __ATOMIC_RELAXED,
                                   __HIP_MEMORY_SCOPE_AGENT) < t + 1)
            __builtin_amdgcn_s_sleep(1);
        }
        __builtin_amdgcn_fence(__ATOMIC_ACQUIRE, "agent");
      }
      __syncthreads();
    }
  }
}

// ---------------------------------------------------------------------------
extern "C" void kernel_launch(void* const* d_in, const int* in_sizes, int n_in,
                              void* d_out, int out_size, void* d_ws,
                              size_t ws_size, hipStream_t stream) {
  const float* in_seq  = (const float*)d_in[0];  // (64,512,1024)
  const float* W_lower = (const float*)d_in[1];  // (1024,1024)
  const float* W_input = (const float*)d_in[2];  // (1024,1024)
  float* out = (float*)d_out;                    // (64,512,1024)
  float* Ws  = (float*)d_ws;                     // 4 MiB scratch

  symm_k<<<dim3(N / 16, N / 16), 256, 0, stream>>>(W_lower, Ws);
  xproj_gemm<<<dim3(N / 128, (BATCH * T) / 128), 256, 0, stream>>>(
      in_seq, W_input, out, BATCH * T);
  rnn_persist<<<NWG, 256, 0, stream>>>(out, Ws);
}

// Round 7
// 4287.101 us; speedup vs baseline: 3.1247x; 1.9462x over previous
//
#include <hip/hip_runtime.h>
#include <cstdint>
#include <cmath>

constexpr int BATCH = 64;
constexpr int T     = 512;
constexpr int N     = 1024;
constexpr int NWG   = 256;   // persistent workgroups (== CU count)
constexpr int MB    = 16;    // batches per WG
constexpr int MM    = 16;    // output columns per WG
constexpr int NP    = N + 4; // padded LDS row (breaks 32-bank stride)

typedef float f4 __attribute__((ext_vector_type(4)));

struct alignas(128) PadInt { int v; int pad[31]; };
__device__ PadInt g_cnt[4];   // per-batch-group arrival counters
__device__ PadInt g_flag[4];  // per-batch-group release epochs

// ---- MALL-coherent access helpers (bypass L1+L2: no stale line can serve) --
__device__ __forceinline__ f4 ld_sys_x4(const float* p) {
  f4 v;
  asm volatile("global_load_dwordx4 %0, %1, off sc0 sc1" : "=v"(v) : "v"(p));
  return v;  // NOT ready until an explicit s_waitcnt vmcnt(0)!
}
__device__ __forceinline__ float ld_sys(const float* p) {
  float v;
  asm volatile("global_load_dword %0, %1, off sc0 sc1" : "=v"(v) : "v"(p));
  return v;  // NOT ready until an explicit s_waitcnt vmcnt(0)!
}
__device__ __forceinline__ void st_sys(float* p, float v) {
  asm volatile("global_store_dword %0, %1, off sc0 sc1 nt" ::"v"(p), "v"(v)
               : "memory");
}
__device__ __forceinline__ void wait_vm0(void) {
  asm volatile("s_waitcnt vmcnt(0)" ::: "memory");
  __builtin_amdgcn_sched_barrier(0);
}

// ---------------------------------------------------------------------------
// W_self = 0.5*(W + W^T); also re-initializes the barrier state.
// ---------------------------------------------------------------------------
__global__ __launch_bounds__(256) void symm_k(const float* __restrict__ W,
                                              float* __restrict__ Ws) {
  if (blockIdx.x == 0 && blockIdx.y == 0 && threadIdx.x < 4) {
    __hip_atomic_store(&g_cnt[threadIdx.x].v, 0, __ATOMIC_RELAXED,
                       __HIP_MEMORY_SCOPE_AGENT);
    __hip_atomic_store(&g_flag[threadIdx.x].v, 0, __ATOMIC_RELAXED,
                       __HIP_MEMORY_SCOPE_AGENT);
  }
  int j = blockIdx.x * 16 + (threadIdx.x & 15);
  int i = blockIdx.y * 16 + (threadIdx.x >> 4);
  Ws[(size_t)i * N + j] = 0.5f * (W[(size_t)i * N + j] + W[(size_t)j * N + i]);
}

// ---------------------------------------------------------------------------
// x_proj = A (M x K) . B^T, B = W_input (N x K) row-major. 128x128 tile.
// ---------------------------------------------------------------------------
__global__ __launch_bounds__(256) void xproj_gemm(const float* __restrict__ A,
                                                  const float* __restrict__ B,
                                                  float* __restrict__ C,
                                                  int M) {
  constexpr int BM = 128, BN = 128, BK = 16;
  __shared__ float As[BK][BM + 4];
  __shared__ float Bs[BK][BN + 4];

  const int tid = threadIdx.x;
  const int bm = blockIdx.y, bn = blockIdx.x;
  const int tx = tid & 15, ty = tid >> 4;
  const int K = N;

  float acc[8][8];
#pragma unroll
  for (int i = 0; i < 8; ++i)
#pragma unroll
    for (int j = 0; j < 8; ++j) acc[i][j] = 0.f;

  for (int kt = 0; kt < K; kt += BK) {
#pragma unroll
    for (int s = 0; s < 2; ++s) {
      int f = tid + s * 256;
      int row = f >> 2, kq = f & 3;
      float4 a = *reinterpret_cast<const float4*>(
          &A[(size_t)(bm * BM + row) * K + kt + kq * 4]);
      As[kq * 4 + 0][row] = a.x;
      As[kq * 4 + 1][row] = a.y;
      As[kq * 4 + 2][row] = a.z;
      As[kq * 4 + 3][row] = a.w;
      float4 b = *reinterpret_cast<const float4*>(
          &B[(size_t)(bn * BN + row) * K + kt + kq * 4]);
      Bs[kq * 4 + 0][row] = b.x;
      Bs[kq * 4 + 1][row] = b.y;
      Bs[kq * 4 + 2][row] = b.z;
      Bs[kq * 4 + 3][row] = b.w;
    }
    __syncthreads();

#pragma unroll
    for (int k = 0; k < BK; ++k) {
      float a[8], b[8];
      *reinterpret_cast<float4*>(&a[0]) =
          *reinterpret_cast<const float4*>(&As[k][ty * 8]);
      *reinterpret_cast<float4*>(&a[4]) =
          *reinterpret_cast<const float4*>(&As[k][ty * 8 + 4]);
      *reinterpret_cast<float4*>(&b[0]) =
          *reinterpret_cast<const float4*>(&Bs[k][tx * 8]);
      *reinterpret_cast<float4*>(&b[4]) =
          *reinterpret_cast<const float4*>(&Bs[k][tx * 8 + 4]);
#pragma unroll
      for (int i = 0; i < 8; ++i)
#pragma unroll
        for (int j = 0; j < 8; ++j) acc[i][j] = fmaf(a[i], b[j], acc[i][j]);
    }
    __syncthreads();
  }

#pragma unroll
  for (int i = 0; i < 8; ++i) {
    size_t row = (size_t)bm * BM + ty * 8 + i;
#pragma unroll
    for (int j = 0; j < 8; j += 4) {
      *reinterpret_cast<float4*>(&C[row * N + bn * BN + tx * 8 + j]) =
          *reinterpret_cast<const float4*>(&acc[i][j]);
    }
  }
}

// ---------------------------------------------------------------------------
// Persistent recurrence.  Grid = 256 WGs x 256 threads, 1 WG/CU.
// WG (bg,mg): batches bg*16.., cols mg*16..; W slice resident in LDS.
// 4 independent 64-WG barriers (one per batch group), RELAXED atomics only.
// Correctness without fences: ALL out-accesses are sc0+sc1 (MALL-coherent,
// bypass L1/L2 so stale clean lines can never serve); __syncthreads' vmcnt(0)
// drains the write-through stores to MALL before the arrival RMW.
// ---------------------------------------------------------------------------
__global__ __launch_bounds__(256) void rnn_persist(float* __restrict__ out,
                                                   const float* __restrict__ Ws) {
  const int tid = threadIdx.x;
  const int wg  = blockIdx.x;
  const int mg  = wg >> 2;          // 64 column groups
  const int bg  = wg & 3;           // 4 batch groups
  const int m0  = mg * MM;
  const int b0  = bg * MB;
  const size_t TN = (size_t)T * N;

  __shared__ float Wl[MM][NP];      // ~64 KiB, persistent, padded
  __shared__ float hl[MB][NP];      // ~64 KiB, per-step h slice, padded
  __shared__ float pre[MB][MM + 1]; // reduced preactivation

  // ---- load W slice once (row-wise, coalesced; plain loads are fine:
  //      Ws written by symm_k in a prior dispatch, never rewritten) ----
#pragma unroll
  for (int r = 0; r < MM; ++r) {
    const float4* src = reinterpret_cast<const float4*>(Ws + (size_t)(m0 + r) * N);
    reinterpret_cast<float4*>(&Wl[r][0])[tid] = src[tid];
  }

  const int l  = tid & 63;          // lane
  const int w  = tid >> 6;          // wave -> batch quad
  const int tw = l & 3;             // m quad
  const int kp = l >> 2;            // k partition (16-way)
  const int rs = tid >> 4;          // output row (batch-local)
  const int cs = tid & 15;          // output col

  float* myout = out + (size_t)(b0 + rs) * TN + m0 + cs;

  // prefetch xp for t=0
  float xpr = ld_sys(myout);
  wait_vm0();

  for (int t = 0; t < T; ++t) {
    if (t > 0) {
      const float* hsrc =
          out + (size_t)(b0 + rs) * TN + (size_t)(t - 1) * N;
      // issue all 16 coherent x4 loads, then one wait (rule-18 pattern)
      f4 tmp[16];
#pragma unroll
      for (int jj = 0; jj < 16; ++jj)
        tmp[jj] = ld_sys_x4(hsrc + 4 * (cs + 16 * jj));
      wait_vm0();
      f4* hdst = reinterpret_cast<f4*>(&hl[rs][0]);
#pragma unroll
      for (int jj = 0; jj < 16; ++jj) hdst[cs + 16 * jj] = tmp[jj];
      __syncthreads();

      float acc[16];
#pragma unroll
      for (int i = 0; i < 16; ++i) acc[i] = 0.f;
#pragma unroll 2
      for (int j = 0; j < 16; ++j) {
        const int kb = j * 64 + kp * 4;
        float4 hv[4], wv[4];
#pragma unroll
        for (int i = 0; i < 4; ++i)
          hv[i] = *reinterpret_cast<const float4*>(&hl[w * 4 + i][kb]);
#pragma unroll
        for (int i = 0; i < 4; ++i)
          wv[i] = *reinterpret_cast<const float4*>(&Wl[tw * 4 + i][kb]);
#pragma unroll
        for (int bi = 0; bi < 4; ++bi)
#pragma unroll
          for (int mi = 0; mi < 4; ++mi) {
            float a = acc[bi * 4 + mi];
            a = fmaf(hv[bi].x, wv[mi].x, a);
            a = fmaf(hv[bi].y, wv[mi].y, a);
            a = fmaf(hv[bi].z, wv[mi].z, a);
            a = fmaf(hv[bi].w, wv[mi].w, a);
            acc[bi * 4 + mi] = a;
          }
      }
      // reduce over the 16 k-partitions (lanes differing in bits 2..5)
#pragma unroll
      for (int o = 4; o < 64; o <<= 1)
#pragma unroll
        for (int i = 0; i < 16; ++i) acc[i] += __shfl_xor(acc[i], o, 64);
      if (kp == 0) {
#pragma unroll
        for (int bi = 0; bi < 4; ++bi)
#pragma unroll
          for (int mi = 0; mi < 4; ++mi)
            pre[w * 4 + bi][tw * 4 + mi] = acc[bi * 4 + mi];
      }
      __syncthreads();
    }

    float pv = (t > 0) ? (pre[rs][cs] + xpr) : xpr;
    st_sys(myout + (size_t)t * N, tanhf(pv));  // write-through to MALL

    if (t < T - 1) {
      // prefetch next xp (own tile; only this WG ever writes it)
      xpr = ld_sys(myout + (size_t)(t + 1) * N);
      wait_vm0();       // xp loaded AND all h_t stores complete at MALL
      __syncthreads();  // whole WG done storing
      if (tid == 0) {
        int old = __hip_atomic_fetch_add(&g_cnt[bg].v, 1, __ATOMIC_RELAXED,
                                         __HIP_MEMORY_SCOPE_AGENT);
        if (old == (t + 1) * 64 - 1) {
          // last arriver in this batch group: publish epoch
          __hip_atomic_store(&g_flag[bg].v, t + 1, __ATOMIC_RELAXED,
                             __HIP_MEMORY_SCOPE_AGENT);
        } else {
          // relaxed RMW poll executes at MALL -> always fresh
          while (__hip_atomic_fetch_add(&g_flag[bg].v, 0, __ATOMIC_RELAXED,
                                        __HIP_MEMORY_SCOPE_AGENT) < t + 1)
            __builtin_amdgcn_s_sleep(2);
        }
      }
      __syncthreads();
    }
  }
}

// ---------------------------------------------------------------------------
extern "C" void kernel_launch(void* const* d_in, const int* in_sizes, int n_in,
                              void* d_out, int out_size, void* d_ws,
                              size_t ws_size, hipStream_t stream) {
  const float* in_seq  = (const float*)d_in[0];  // (64,512,1024)
  const float* W_lower = (const float*)d_in[1];  // (1024,1024)
  const float* W_input = (const float*)d_in[2];  // (1024,1024)
  float* out = (float*)d_out;                    // (64,512,1024)
  float* Ws  = (float*)d_ws;                     // 4 MiB scratch

  symm_k<<<dim3(N / 16, N / 16), 256, 0, stream>>>(W_lower, Ws);
  xproj_gemm<<<dim3(N / 128, (BATCH * T) / 128), 256, 0, stream>>>(
      in_seq, W_input, out, BATCH * T);
  rnn_persist<<<NWG, 256, 0, stream>>>(out, Ws);
}

// Round 8
// 4282.071 us; speedup vs baseline: 3.1284x; 1.0012x over previous
//
#include <hip/hip_runtime.h>
#include <cstdint>
#include <cmath>

constexpr int BATCH = 64;
constexpr int T     = 512;
constexpr int N     = 1024;
constexpr int NWG   = 256;   // persistent workgroups (== CU count)
constexpr int MB    = 16;    // batches per WG
constexpr int MM    = 16;    // output columns per WG
constexpr int NP    = N + 4; // padded LDS row (breaks 32-bank stride)

typedef float f4 __attribute__((ext_vector_type(4)));

struct alignas(128) PadInt { int v; int pad[31]; };
__device__ PadInt g_leaf[4][8];  // per-group leaf arrival counters (8 x 8 WGs)
__device__ PadInt g_cnt[4];      // per-group root counters (8 leaves/step)
__device__ PadInt g_flag[4];     // per-group release epochs

// ---- MALL-coherent access helpers (bypass L1+L2: no stale line can serve) --
__device__ __forceinline__ f4 ld_sys_x4(const float* p) {
  f4 v;
  asm volatile("global_load_dwordx4 %0, %1, off sc0 sc1" : "=v"(v) : "v"(p));
  return v;  // NOT ready until an explicit s_waitcnt!
}
__device__ __forceinline__ float ld_sys(const float* p) {
  float v;
  asm volatile("global_load_dword %0, %1, off sc0 sc1" : "=v"(v) : "v"(p));
  return v;  // NOT ready until an explicit s_waitcnt!
}
__device__ __forceinline__ int ld_sys_i32(const int* p) {
  int v;
  asm volatile("global_load_dword %0, %1, off sc0 sc1\n\ts_waitcnt vmcnt(0)"
               : "=v"(v) : "v"(p) : "memory");
  return v;
}
__device__ __forceinline__ void st_sys(float* p, float v) {
  asm volatile("global_store_dword %0, %1, off sc0 sc1 nt" ::"v"(p), "v"(v)
               : "memory");
}
__device__ __forceinline__ void wait_vm0(void) {
  asm volatile("s_waitcnt vmcnt(0)" ::: "memory");
  __builtin_amdgcn_sched_barrier(0);
}
__device__ __forceinline__ void wait_vm1(void) {
  // FIFO vmcnt: waits until <=1 op outstanding -> all but the newest complete.
  asm volatile("s_waitcnt vmcnt(1)" ::: "memory");
  __builtin_amdgcn_sched_barrier(0);
}

// ---------------------------------------------------------------------------
// W_self = 0.5*(W + W^T); also re-initializes the barrier state.
// ---------------------------------------------------------------------------
__global__ __launch_bounds__(256) void symm_k(const float* __restrict__ W,
                                              float* __restrict__ Ws) {
  if (blockIdx.x == 0 && blockIdx.y == 0) {
    if (threadIdx.x < 32)
      __hip_atomic_store(&g_leaf[threadIdx.x >> 3][threadIdx.x & 7].v, 0,
                         __ATOMIC_RELAXED, __HIP_MEMORY_SCOPE_AGENT);
    if (threadIdx.x < 4) {
      __hip_atomic_store(&g_cnt[threadIdx.x].v, 0, __ATOMIC_RELAXED,
                         __HIP_MEMORY_SCOPE_AGENT);
      __hip_atomic_store(&g_flag[threadIdx.x].v, 0, __ATOMIC_RELAXED,
                         __HIP_MEMORY_SCOPE_AGENT);
    }
  }
  int j = blockIdx.x * 16 + (threadIdx.x & 15);
  int i = blockIdx.y * 16 + (threadIdx.x >> 4);
  Ws[(size_t)i * N + j] = 0.5f * (W[(size_t)i * N + j] + W[(size_t)j * N + i]);
}

// ---------------------------------------------------------------------------
// x_proj = A (M x K) . B^T, B = W_input (N x K) row-major. 128x128 tile.
// ---------------------------------------------------------------------------
__global__ __launch_bounds__(256) void xproj_gemm(const float* __restrict__ A,
                                                  const float* __restrict__ B,
                                                  float* __restrict__ C,
                                                  int M) {
  constexpr int BM = 128, BN = 128, BK = 16;
  __shared__ float As[BK][BM + 4];
  __shared__ float Bs[BK][BN + 4];

  const int tid = threadIdx.x;
  const int bm = blockIdx.y, bn = blockIdx.x;
  const int tx = tid & 15, ty = tid >> 4;
  const int K = N;

  float acc[8][8];
#pragma unroll
  for (int i = 0; i < 8; ++i)
#pragma unroll
    for (int j = 0; j < 8; ++j) acc[i][j] = 0.f;

  for (int kt = 0; kt < K; kt += BK) {
#pragma unroll
    for (int s = 0; s < 2; ++s) {
      int f = tid + s * 256;
      int row = f >> 2, kq = f & 3;
      float4 a = *reinterpret_cast<const float4*>(
          &A[(size_t)(bm * BM + row) * K + kt + kq * 4]);
      As[kq * 4 + 0][row] = a.x;
      As[kq * 4 + 1][row] = a.y;
      As[kq * 4 + 2][row] = a.z;
      As[kq * 4 + 3][row] = a.w;
      float4 b = *reinterpret_cast<const float4*>(
          &B[(size_t)(bn * BN + row) * K + kt + kq * 4]);
      Bs[kq * 4 + 0][row] = b.x;
      Bs[kq * 4 + 1][row] = b.y;
      Bs[kq * 4 + 2][row] = b.z;
      Bs[kq * 4 + 3][row] = b.w;
    }
    __syncthreads();

#pragma unroll
    for (int k = 0; k < BK; ++k) {
      float a[8], b[8];
      *reinterpret_cast<float4*>(&a[0]) =
          *reinterpret_cast<const float4*>(&As[k][ty * 8]);
      *reinterpret_cast<float4*>(&a[4]) =
          *reinterpret_cast<const float4*>(&As[k][ty * 8 + 4]);
      *reinterpret_cast<float4*>(&b[0]) =
          *reinterpret_cast<const float4*>(&Bs[k][tx * 8]);
      *reinterpret_cast<float4*>(&b[4]) =
          *reinterpret_cast<const float4*>(&Bs[k][tx * 8 + 4]);
#pragma unroll
      for (int i = 0; i < 8; ++i)
#pragma unroll
        for (int j = 0; j < 8; ++j) acc[i][j] = fmaf(a[i], b[j], acc[i][j]);
    }
    __syncthreads();
  }

#pragma unroll
  for (int i = 0; i < 8; ++i) {
    size_t row = (size_t)bm * BM + ty * 8 + i;
#pragma unroll
    for (int j = 0; j < 8; j += 4) {
      *reinterpret_cast<float4*>(&C[row * N + bn * BN + tx * 8 + j]) =
          *reinterpret_cast<const float4*>(&acc[i][j]);
    }
  }
}

// ---------------------------------------------------------------------------
// Persistent recurrence.  Grid = 256 WGs x 256 threads, 1 WG/CU.
// WG (bg,mg): batches bg*16.., cols mg*16..; W slice resident in LDS.
// 4 independent 64-WG barriers, hierarchical: 8 leaves x 8 WGs -> root ->
// flag.  RELAXED atomics only; waiters poll flag with plain sc0+sc1 loads
// (no RMW serialization).  Data path: all out-accesses sc0+sc1 (MALL-
// coherent), stores drained via vmcnt before arrival.
// ---------------------------------------------------------------------------
__global__ __launch_bounds__(256) void rnn_persist(float* __restrict__ out,
                                                   const float* __restrict__ Ws) {
  const int tid = threadIdx.x;
  const int wg  = blockIdx.x;
  const int mg  = wg >> 2;          // 64 column groups
  const int bg  = wg & 3;           // 4 batch groups
  const int m0  = mg * MM;
  const int b0  = bg * MB;
  const size_t TN = (size_t)T * N;

  __shared__ float Wl[MM][NP];      // ~64 KiB, persistent, padded
  __shared__ float hl[MB][NP];      // ~64 KiB, per-step h slice, padded
  __shared__ float pre[MB][MM + 1]; // reduced preactivation

  // ---- load W slice once (row-wise, coalesced; plain loads fine: Ws is
  //      written by a prior dispatch and never rewritten) ----
#pragma unroll
  for (int r = 0; r < MM; ++r) {
    const float4* src = reinterpret_cast<const float4*>(Ws + (size_t)(m0 + r) * N);
    reinterpret_cast<float4*>(&Wl[r][0])[tid] = src[tid];
  }

  const int l  = tid & 63;          // lane
  const int w  = tid >> 6;          // wave -> batch quad
  const int tw = l & 3;             // m quad
  const int kp = l >> 2;            // k partition (16-way)
  const int rs = tid >> 4;          // output row (batch-local)
  const int cs = tid & 15;          // output col

  float* myout = out + (size_t)(b0 + rs) * TN + m0 + cs;

  // prefetch xp for t=0
  float xpr = ld_sys(myout);
  wait_vm0();

  for (int t = 0; t < T; ++t) {
    if (t > 0) {
      const float* hsrc =
          out + (size_t)(b0 + rs) * TN + (size_t)(t - 1) * N;
      // issue all 16 coherent x4 loads, then one wait (rule-18 pattern).
      // This vmcnt(0) also collects the in-flight xp prefetch from t-1.
      f4 tmp[16];
#pragma unroll
      for (int jj = 0; jj < 16; ++jj)
        tmp[jj] = ld_sys_x4(hsrc + 4 * (cs + 16 * jj));
      wait_vm0();
      f4* hdst = reinterpret_cast<f4*>(&hl[rs][0]);
#pragma unroll
      for (int jj = 0; jj < 16; ++jj) hdst[cs + 16 * jj] = tmp[jj];
      __syncthreads();

      float acc[16];
#pragma unroll
      for (int i = 0; i < 16; ++i) acc[i] = 0.f;
#pragma unroll 2
      for (int j = 0; j < 16; ++j) {
        const int kb = j * 64 + kp * 4;
        float4 hv[4], wv[4];
#pragma unroll
        for (int i = 0; i < 4; ++i)
          hv[i] = *reinterpret_cast<const float4*>(&hl[w * 4 + i][kb]);
#pragma unroll
        for (int i = 0; i < 4; ++i)
          wv[i] = *reinterpret_cast<const float4*>(&Wl[tw * 4 + i][kb]);
#pragma unroll
        for (int bi = 0; bi < 4; ++bi)
#pragma unroll
          for (int mi = 0; mi < 4; ++mi) {
            float a = acc[bi * 4 + mi];
            a = fmaf(hv[bi].x, wv[mi].x, a);
            a = fmaf(hv[bi].y, wv[mi].y, a);
            a = fmaf(hv[bi].z, wv[mi].z, a);
            a = fmaf(hv[bi].w, wv[mi].w, a);
            acc[bi * 4 + mi] = a;
          }
      }
      // reduce over the 16 k-partitions (lanes differing in bits 2..5)
#pragma unroll
      for (int o = 4; o < 64; o <<= 1)
#pragma unroll
        for (int i = 0; i < 16; ++i) acc[i] += __shfl_xor(acc[i], o, 64);
      if (kp == 0) {
#pragma unroll
        for (int bi = 0; bi < 4; ++bi)
#pragma unroll
          for (int mi = 0; mi < 4; ++mi)
            pre[w * 4 + bi][tw * 4 + mi] = acc[bi * 4 + mi];
      }
      __syncthreads();
    }

    float pv = (t > 0) ? (pre[rs][cs] + xpr) : xpr;
    st_sys(myout + (size_t)t * N, tanhf(pv));  // write-through to MALL

    if (t < T - 1) {
      // issue next-xp prefetch, then wait only for the STORE (vmcnt(1):
      // newest op = the load stays in flight through the barrier).
      xpr = ld_sys(myout + (size_t)(t + 1) * N);
      wait_vm1();
      __syncthreads();  // whole WG done storing h_t
      if (tid == 0) {
        const int leaf = mg & 7;
        bool published = false;
        int old = __hip_atomic_fetch_add(&g_leaf[bg][leaf].v, 1,
                                         __ATOMIC_RELAXED,
                                         __HIP_MEMORY_SCOPE_AGENT);
        if (old == (t + 1) * 8 - 1) {  // leaf closer
          int r = __hip_atomic_fetch_add(&g_cnt[bg].v, 1, __ATOMIC_RELAXED,
                                         __HIP_MEMORY_SCOPE_AGENT);
          if (r == (t + 1) * 8 - 1) {  // root closer: publish epoch
            __hip_atomic_store(&g_flag[bg].v, t + 1, __ATOMIC_RELAXED,
                               __HIP_MEMORY_SCOPE_AGENT);
            published = true;
          }
        }
        if (!published) {
          // read-only MALL poll: no RMW serialization among waiters
          while (ld_sys_i32(&g_flag[bg].v) < t + 1)
            __builtin_amdgcn_s_sleep(1);
        }
      }
      __syncthreads();
    }
  }
}

// ---------------------------------------------------------------------------
extern "C" void kernel_launch(void* const* d_in, const int* in_sizes, int n_in,
                              void* d_out, int out_size, void* d_ws,
                              size_t ws_size, hipStream_t stream) {
  const float* in_seq  = (const float*)d_in[0];  // (64,512,1024)
  const float* W_lower = (const float*)d_in[1];  // (1024,1024)
  const float* W_input = (const float*)d_in[2];  // (1024,1024)
  float* out = (float*)d_out;                    // (64,512,1024)
  float* Ws  = (float*)d_ws;                     // 4 MiB scratch

  symm_k<<<dim3(N / 16, N / 16), 256, 0, stream>>>(W_lower, Ws);
  xproj_gemm<<<dim3(N / 128, (BATCH * T) / 128), 256, 0, stream>>>(
      in_seq, W_input, out, BATCH * T);
  rnn_persist<<<NWG, 256, 0, stream>>>(out, Ws);
}

// Round 9
// 3916.637 us; speedup vs baseline: 3.4202x; 1.0933x over previous
//
#include <hip/hip_runtime.h>
#include <cstdint>
#include <cmath>

constexpr int BATCH = 64;
constexpr int T     = 512;
constexpr int N     = 1024;
constexpr int NWG   = 256;   // persistent workgroups (== CU count)
constexpr int NP    = N + 4; // padded LDS row

typedef float f4 __attribute__((ext_vector_type(4)));

struct alignas(128) PadInt { int v; int pad[31]; };
__device__ PadInt g_cnt[8];   // per-batch-group arrival counters (cumulative)
__device__ PadInt g_flag[8];  // per-batch-group completed-step counters

// ---- MALL-coherent access helpers (bypass L1+L2) ---------------------------
__device__ __forceinline__ f4 ld_sys_x4(const float* p) {
  f4 v;
  asm volatile("global_load_dwordx4 %0, %1, off sc0 sc1" : "=v"(v) : "v"(p));
  return v;  // NOT ready until wait_vm0()
}
__device__ __forceinline__ float ld_sys(const float* p) {
  float v;
  asm volatile("global_load_dword %0, %1, off sc0 sc1" : "=v"(v) : "v"(p));
  return v;  // NOT ready until wait_vm0()
}
__device__ __forceinline__ int ld_sys_i32(const int* p) {
  int v;
  asm volatile("global_load_dword %0, %1, off sc0 sc1\n\ts_waitcnt vmcnt(0)"
               : "=v"(v) : "v"(p) : "memory");
  return v;
}
__device__ __forceinline__ void st_sys(float* p, float v) {
  asm volatile("global_store_dword %0, %1, off sc0 sc1 nt" ::"v"(p), "v"(v)
               : "memory");
}
__device__ __forceinline__ void wait_vm0(void) {
  asm volatile("s_waitcnt vmcnt(0)" ::: "memory");
  __builtin_amdgcn_sched_barrier(0);
}

__device__ __forceinline__ void arrive_cnt(int bg, int t) {
  int old = __hip_atomic_fetch_add(&g_cnt[bg].v, 1, __ATOMIC_RELAXED,
                                   __HIP_MEMORY_SCOPE_AGENT);
  if (old == t * 64 + 63)  // last arriver of this step: publish
    __hip_atomic_store(&g_flag[bg].v, t + 1, __ATOMIC_RELAXED,
                       __HIP_MEMORY_SCOPE_AGENT);
}
__device__ __forceinline__ void pollf(int bg, int e) {
  while (ld_sys_i32(&g_flag[bg].v) < e) __builtin_amdgcn_s_sleep(1);
}

// ---------------------------------------------------------------------------
// W_self = 0.5*(W + W^T); also re-initializes the barrier state.
// ---------------------------------------------------------------------------
__global__ __launch_bounds__(256) void symm_k(const float* __restrict__ W,
                                              float* __restrict__ Ws) {
  if (blockIdx.x == 0 && blockIdx.y == 0 && threadIdx.x < 8) {
    __hip_atomic_store(&g_cnt[threadIdx.x].v, 0, __ATOMIC_RELAXED,
                       __HIP_MEMORY_SCOPE_AGENT);
    __hip_atomic_store(&g_flag[threadIdx.x].v, 0, __ATOMIC_RELAXED,
                       __HIP_MEMORY_SCOPE_AGENT);
  }
  int j = blockIdx.x * 16 + (threadIdx.x & 15);
  int i = blockIdx.y * 16 + (threadIdx.x >> 4);
  Ws[(size_t)i * N + j] = 0.5f * (W[(size_t)i * N + j] + W[(size_t)j * N + i]);
}

// ---------------------------------------------------------------------------
// x_proj = A (M x K) . B^T, B = W_input (N x K) row-major. 128x128 tile.
// ---------------------------------------------------------------------------
__global__ __launch_bounds__(256) void xproj_gemm(const float* __restrict__ A,
                                                  const float* __restrict__ B,
                                                  float* __restrict__ C,
                                                  int M) {
  constexpr int BM = 128, BN = 128, BK = 16;
  __shared__ float As[BK][BM + 4];
  __shared__ float Bs[BK][BN + 4];

  const int tid = threadIdx.x;
  const int bm = blockIdx.y, bn = blockIdx.x;
  const int tx = tid & 15, ty = tid >> 4;
  const int K = N;

  float acc[8][8];
#pragma unroll
  for (int i = 0; i < 8; ++i)
#pragma unroll
    for (int j = 0; j < 8; ++j) acc[i][j] = 0.f;

  for (int kt = 0; kt < K; kt += BK) {
#pragma unroll
    for (int s = 0; s < 2; ++s) {
      int f = tid + s * 256;
      int row = f >> 2, kq = f & 3;
      float4 a = *reinterpret_cast<const float4*>(
          &A[(size_t)(bm * BM + row) * K + kt + kq * 4]);
      As[kq * 4 + 0][row] = a.x;
      As[kq * 4 + 1][row] = a.y;
      As[kq * 4 + 2][row] = a.z;
      As[kq * 4 + 3][row] = a.w;
      float4 b = *reinterpret_cast<const float4*>(
          &B[(size_t)(bn * BN + row) * K + kt + kq * 4]);
      Bs[kq * 4 + 0][row] = b.x;
      Bs[kq * 4 + 1][row] = b.y;
      Bs[kq * 4 + 2][row] = b.z;
      Bs[kq * 4 + 3][row] = b.w;
    }
    __syncthreads();

#pragma unroll
    for (int k = 0; k < BK; ++k) {
      float a[8], b[8];
      *reinterpret_cast<float4*>(&a[0]) =
          *reinterpret_cast<const float4*>(&As[k][ty * 8]);
      *reinterpret_cast<float4*>(&a[4]) =
          *reinterpret_cast<const float4*>(&As[k][ty * 8 + 4]);
      *reinterpret_cast<float4*>(&b[0]) =
          *reinterpret_cast<const float4*>(&Bs[k][tx * 8]);
      *reinterpret_cast<float4*>(&b[4]) =
          *reinterpret_cast<const float4*>(&Bs[k][tx * 8 + 4]);
#pragma unroll
      for (int i = 0; i < 8; ++i)
#pragma unroll
        for (int j = 0; j < 8; ++j) acc[i][j] = fmaf(a[i], b[j], acc[i][j]);
    }
    __syncthreads();
  }

#pragma unroll
  for (int i = 0; i < 8; ++i) {
    size_t row = (size_t)bm * BM + ty * 8 + i;
#pragma unroll
    for (int j = 0; j < 8; j += 4) {
      *reinterpret_cast<float4*>(&C[row * N + bn * BN + tx * 8 + j]) =
          *reinterpret_cast<const float4*>(&acc[i][j]);
    }
  }
}

// ---------------------------------------------------------------------------
// Persistent recurrence, dual-chain ping-pong + W in registers.
// 256 WGs x 256 thr, 1 WG/CU (LDS 100 KiB).  WG (p = wg&3, cg = wg>>2):
// cols cg*16..+15 for TWO batch groups bgA=2p (batches 8*bgA..+7) and
// bgB=2p+1.  W fragment (2 cols x 64 k per thread) lives in VGPRs for all
// 512 steps.  Chain A's barrier/store latency hides under chain B's work.
// 8 independent 64-WG barriers, relaxed atomics, MALL-coherent data path
// (sc0 sc1 loads / write-through nt stores) as proven in R7/R8.
// ---------------------------------------------------------------------------
__global__ __launch_bounds__(256) void rnn_persist(float* __restrict__ out,
                                                   const float* __restrict__ Ws) {
  const int tid = threadIdx.x;
  const int wg  = blockIdx.x;
  const int p   = wg & 3;
  const int cg  = wg >> 2;
  const int bgA = 2 * p, bgB = 2 * p + 1;
  const int m0  = cg * 16;
  const int b0A = bgA * 8, b0B = bgB * 8;
  const size_t TN = (size_t)T * N;

  // 100 KiB forced LDS (1 WG/CU).  W-staging phase aliases the h buffers.
  __shared__ __align__(16) char lds_raw[102400];
  float (*Wl)[NP]   = reinterpret_cast<float(*)[NP]>(lds_raw);
  float (*hA)[NP]   = reinterpret_cast<float(*)[NP]>(lds_raw);
  float (*hB)[NP]   = reinterpret_cast<float(*)[NP]>(lds_raw + 8 * NP * 4);
  float (*preA)[17] = reinterpret_cast<float(*)[17]>(lds_raw + 16 * NP * 4);
  float (*preB)[17] = reinterpret_cast<float(*)[17]>(lds_raw + 16 * NP * 4 + 544);

  const int l  = tid & 63;
  const int v  = tid >> 6;
  const int kp = l >> 2;            // k partition (16-way)
  const int c2 = l & 3;
  const int bh = v & 1;             // batch half (4 rows)
  const int cp = (v >> 1) * 4 + c2; // col pair 0..7
  const int rs = tid >> 4;          // store row (tid<128)
  const int cs = tid & 15;          // store col

  // ---- W slice -> LDS (coalesced) -> per-thread register fragment ----
#pragma unroll
  for (int r = 0; r < 16; ++r)
    *reinterpret_cast<float4*>(&Wl[r][tid * 4]) =
        *reinterpret_cast<const float4*>(&Ws[(size_t)(m0 + r) * N + tid * 4]);
  __syncthreads();
  f4 wreg[2][16];  // rows (cols of output) cp*2, cp*2+1; k = kp*4 + 64*j
#pragma unroll
  for (int ci = 0; ci < 2; ++ci)
#pragma unroll
    for (int j = 0; j < 16; ++j)
      wreg[ci][j] =
          *reinterpret_cast<const f4*>(&Wl[cp * 2 + ci][kp * 4 + 64 * j]);
  __syncthreads();  // LDS now reused as hA/hB

  float* myoutA = out + (size_t)(b0A + rs) * TN + m0 + cs;
  float* myoutB = out + (size_t)(b0B + rs) * TN + m0 + cs;
  float xpA = 0.f, xpB = 0.f;

  // ---- t = 0: h_0 = tanh(x_proj_0) ----
  if (tid < 128) { xpA = ld_sys(myoutA); xpB = ld_sys(myoutB); }
  wait_vm0();
  if (tid < 128) {
    st_sys(myoutA, tanhf(xpA));
    st_sys(myoutB, tanhf(xpB));
  }
  wait_vm0();
  __syncthreads();
  if (tid == 0)  arrive_cnt(bgA, 0);
  if (tid == 64) arrive_cnt(bgB, 0);
  __syncthreads();
  if (tid == 0)  pollf(bgA, 1);
  __syncthreads();

  for (int t = 1; t < T; ++t) {
    // ================= half A =================
    {
      const float* hsrc =
          out + (size_t)(b0A + (tid >> 5)) * TN + (size_t)(t - 1) * N;
      f4 tmp[8];
#pragma unroll
      for (int q = 0; q < 8; ++q)
        tmp[q] = ld_sys_x4(hsrc + 4 * ((tid & 31) + 32 * q));
      if (tid < 128) xpA = ld_sys(myoutA + (size_t)t * N);
      wait_vm0();
#pragma unroll
      for (int q = 0; q < 8; ++q)
        *reinterpret_cast<f4*>(&hA[tid >> 5][4 * ((tid & 31) + 32 * q)]) =
            tmp[q];
      __syncthreads();

      float acc[8];
#pragma unroll
      for (int i = 0; i < 8; ++i) acc[i] = 0.f;
#pragma unroll
      for (int j = 0; j < 16; ++j) {
        const int kb = kp * 4 + 64 * j;
        f4 hv[4];
#pragma unroll
        for (int bi = 0; bi < 4; ++bi)
          hv[bi] = *reinterpret_cast<const f4*>(&hA[bh * 4 + bi][kb]);
#pragma unroll
        for (int bi = 0; bi < 4; ++bi)
#pragma unroll
          for (int ci = 0; ci < 2; ++ci) {
            float a = acc[bi * 2 + ci];
            a = fmaf(hv[bi].x, wreg[ci][j].x, a);
            a = fmaf(hv[bi].y, wreg[ci][j].y, a);
            a = fmaf(hv[bi].z, wreg[ci][j].z, a);
            a = fmaf(hv[bi].w, wreg[ci][j].w, a);
            acc[bi * 2 + ci] = a;
          }
      }
#pragma unroll
      for (int o = 4; o < 64; o <<= 1)
#pragma unroll
        for (int i = 0; i < 8; ++i) acc[i] += __shfl_xor(acc[i], o, 64);
      if (kp == 0) {
#pragma unroll
        for (int bi = 0; bi < 4; ++bi)
#pragma unroll
          for (int ci = 0; ci < 2; ++ci)
            preA[bh * 4 + bi][cp * 2 + ci] = acc[bi * 2 + ci];
      }
      __syncthreads();
      if (tid < 128) st_sys(myoutA + (size_t)t * N, tanhf(preA[rs][cs] + xpA));
      wait_vm0();
      __syncthreads();
      if (tid == 0)  arrive_cnt(bgA, t);  // concurrent with wave1's poll
      if (tid == 64) pollf(bgB, t);
      __syncthreads();
    }
    // ================= half B =================
    {
      const float* hsrc =
          out + (size_t)(b0B + (tid >> 5)) * TN + (size_t)(t - 1) * N;
      f4 tmp[8];
#pragma unroll
      for (int q = 0; q < 8; ++q)
        tmp[q] = ld_sys_x4(hsrc + 4 * ((tid & 31) + 32 * q));
      if (tid < 128) xpB = ld_sys(myoutB + (size_t)t * N);
      wait_vm0();
#pragma unroll
      for (int q = 0; q < 8; ++q)
        *reinterpret_cast<f4*>(&hB[tid >> 5][4 * ((tid & 31) + 32 * q)]) =
            tmp[q];
      __syncthreads();

      float acc[8];
#pragma unroll
      for (int i = 0; i < 8; ++i) acc[i] = 0.f;
#pragma unroll
      for (int j = 0; j < 16; ++j) {
        const int kb = kp * 4 + 64 * j;
        f4 hv[4];
#pragma unroll
        for (int bi = 0; bi < 4; ++bi)
          hv[bi] = *reinterpret_cast<const f4*>(&hB[bh * 4 + bi][kb]);
#pragma unroll
        for (int bi = 0; bi < 4; ++bi)
#pragma unroll
          for (int ci = 0; ci < 2; ++ci) {
            float a = acc[bi * 2 + ci];
            a = fmaf(hv[bi].x, wreg[ci][j].x, a);
            a = fmaf(hv[bi].y, wreg[ci][j].y, a);
            a = fmaf(hv[bi].z, wreg[ci][j].z, a);
            a = fmaf(hv[bi].w, wreg[ci][j].w, a);
            acc[bi * 2 + ci] = a;
          }
      }
#pragma unroll
      for (int o = 4; o < 64; o <<= 1)
#pragma unroll
        for (int i = 0; i < 8; ++i) acc[i] += __shfl_xor(acc[i], o, 64);
      if (kp == 0) {
#pragma unroll
        for (int bi = 0; bi < 4; ++bi)
#pragma unroll
          for (int ci = 0; ci < 2; ++ci)
            preB[bh * 4 + bi][cp * 2 + ci] = acc[bi * 2 + ci];
      }
      __syncthreads();
      if (tid < 128) st_sys(myoutB + (size_t)t * N, tanhf(preB[rs][cs] + xpB));
      wait_vm0();
      __syncthreads();
      if (tid == 64) arrive_cnt(bgB, t);
      if (tid == 0 && t + 1 < T) pollf(bgA, t + 1);  // pre-poll next iter
      __syncthreads();
    }
  }
}

// ---------------------------------------------------------------------------
extern "C" void kernel_launch(void* const* d_in, const int* in_sizes, int n_in,
                              void* d_out, int out_size, void* d_ws,
                              size_t ws_size, hipStream_t stream) {
  const float* in_seq  = (const float*)d_in[0];  // (64,512,1024)
  const float* W_lower = (const float*)d_in[1];  // (1024,1024)
  const float* W_input = (const float*)d_in[2];  // (1024,1024)
  float* out = (float*)d_out;                    // (64,512,1024)
  float* Ws  = (float*)d_ws;                     // 4 MiB scratch

  symm_k<<<dim3(N / 16, N / 16), 256, 0, stream>>>(W_lower, Ws);
  xproj_gemm<<<dim3(N / 128, (BATCH * T) / 128), 256, 0, stream>>>(
      in_seq, W_input, out, BATCH * T);
  rnn_persist<<<NWG, 256, 0, stream>>>(out, Ws);
}